// Round 1
// baseline (586.708 us; speedup 1.0000x reference)
//
#include <hip/hip_runtime.h>
#include <math.h>

typedef __attribute__((ext_vector_type(8))) _Float16 fp16x8;
typedef __attribute__((ext_vector_type(4))) float floatx4;

#define HID 512
#define TRIC 78
#define OUTC 79
#define BATCH 262144

// ws layout in halfs:
//   W1p frags: [0, 16384)          (32 ntile * 64 lane * 8)   K padded 12->32
//   W2p frags: [16384, 278528)     (32 ntile * 16 kb * 64 * 8)
//   W3p frags: [278528, 319488)    (5 ntile * 16 kb * 64 * 8) N padded 79->80
#define W2P_OFF 16384
#define W3P_OFF 278528

__global__ __launch_bounds__(256) void prep_kernel(const float* __restrict__ W1,
                                                   const float* __restrict__ W2,
                                                   const float* __restrict__ W3,
                                                   _Float16* __restrict__ wsh) {
  int g = blockIdx.x * 256 + threadIdx.x;
  int lane = g & 63;
  int l15 = lane & 15, q = lane >> 4;
  fp16x8 v;
  if (g < 2048) {
    // W1: 12x512, B-frag for 16x16x32: n = nt*16 + (lane&15), k = (lane>>4)*8 + j
    int nt = g >> 6;
    int n = nt * 16 + l15;
#pragma unroll
    for (int j = 0; j < 8; ++j) {
      int k = q * 8 + j;
      v[j] = (k < 12) ? (_Float16)W1[k * HID + n] : (_Float16)0.f;
    }
    *(fp16x8*)(wsh + (size_t)g * 8) = v;
  } else if (g < 34816) {
    // W2: 512x512
    int h = g - 2048;
    int fk = h >> 6;                 // fk = nt*16 + kb
    int kb = fk & 15, nt = fk >> 4;
    int n = nt * 16 + l15;
    int kbase = kb * 32 + q * 8;
#pragma unroll
    for (int j = 0; j < 8; ++j) v[j] = (_Float16)W2[(kbase + j) * HID + n];
    *(fp16x8*)(wsh + W2P_OFF + (size_t)h * 8) = v;
  } else if (g < 39936) {
    // W3: 512x79, pad N to 80
    int h = g - 34816;
    int fk = h >> 6;
    int kb = fk & 15, nt = fk >> 4;
    int n = nt * 16 + l15;
    int kbase = kb * 32 + q * 8;
#pragma unroll
    for (int j = 0; j < 8; ++j)
      v[j] = (n < OUTC) ? (_Float16)W3[(kbase + j) * OUTC + n] : (_Float16)0.f;
    *(fp16x8*)(wsh + W3P_OFF + (size_t)h * 8) = v;
  }
}

__device__ __forceinline__ float softplus_f(float v) {
  return fmaxf(v, 0.f) + log1pf(expf(-fabsf(v)));
}

// hbuf A-frag layout: half index = ((kb*4 + mt)*64 + lane')*8 + j'
// encodes h[m = mt*16 + (lane'&15)][k = kb*32 + (lane'>>4)*8 + j']
__global__ __launch_bounds__(256, 2) void fused_kernel(const float* __restrict__ x,
                                                       const float* __restrict__ b1,
                                                       const float* __restrict__ b2,
                                                       const float* __restrict__ b3,
                                                       const _Float16* __restrict__ wsh,
                                                       float* __restrict__ out) {
  __shared__ _Float16 hbuf[32768];  // 64 KB: h-frags, overlaid with x stage / out tile
  const int tid = threadIdx.x;
  const int wave = tid >> 6, lane = tid & 63;
  const int l15 = lane & 15, quad = lane >> 4;
  const int r0 = blockIdx.x * 64;

  // ---- stage x tile (64 rows x 12 f32, coalesced) into LDS base ----
  float* xf = (float*)hbuf;
  const float* xg = x + (size_t)r0 * 12;
#pragma unroll
  for (int s = 0; s < 3; ++s) xf[tid + s * 256] = xg[tid + s * 256];
  __syncthreads();

  // ---- layer1 A-frags from x (K padded to 32) ----
  fp16x8 xa[4];
#pragma unroll
  for (int mt = 0; mt < 4; ++mt) {
    int row = mt * 16 + l15;
#pragma unroll
    for (int j = 0; j < 8; ++j) {
      int k = quad * 8 + j;
      xa[mt][j] = (k < 12) ? (_Float16)xf[row * 12 + k] : (_Float16)0.f;
    }
  }

  const fp16x8* w1p = (const fp16x8*)wsh;
  const fp16x8* w2p = (const fp16x8*)(wsh + W2P_OFF);
  const fp16x8* w3p = (const fp16x8*)(wsh + W3P_OFF);
  const fp16x8* hfr = (const fp16x8*)hbuf;

  const floatx4 zero4 = {0.f, 0.f, 0.f, 0.f};
  floatx4 acc[4][8];
#pragma unroll
  for (int mt = 0; mt < 4; ++mt)
#pragma unroll
    for (int nt = 0; nt < 8; ++nt) acc[mt][nt] = zero4;

  // ---- layer1 MFMA: h1 = relu(x @ W1 + b1); wave owns 128-col slice ----
#pragma unroll
  for (int nt = 0; nt < 8; ++nt) {
    int ntw = wave * 8 + nt;
    fp16x8 bf = w1p[ntw * 64 + lane];
#pragma unroll
    for (int mt = 0; mt < 4; ++mt)
      acc[mt][nt] = __builtin_amdgcn_mfma_f32_16x16x32_f16(xa[mt], bf, acc[mt][nt], 0, 0, 0);
  }
  float bv[8];
#pragma unroll
  for (int nt = 0; nt < 8; ++nt) bv[nt] = b1[(wave * 8 + nt) * 16 + l15];

  __syncthreads();  // all waves done reading x region

  // ---- epilogue1: relu + bias -> h-frag layout in LDS (fp16) ----
#pragma unroll
  for (int mt = 0; mt < 4; ++mt)
#pragma unroll
    for (int nt = 0; nt < 8; ++nt) {
      int kg = (wave * 8 + nt) * 16 + l15;
      int kb = kg >> 5, k32 = kg & 31;
      int lp = (k32 >> 3) << 4;
#pragma unroll
      for (int r = 0; r < 4; ++r) {
        float v = fmaxf(acc[mt][nt][r] + bv[nt], 0.f);
        hbuf[(((kb * 4 + mt) * 64) + ((quad * 4 + r) | lp)) * 8 + (k32 & 7)] = (_Float16)v;
      }
    }
  __syncthreads();

  // ---- layer2: h2 = relu(h1 @ W2 + b2). No barrier in K-loop; W2 frags from L2 ----
#pragma unroll
  for (int mt = 0; mt < 4; ++mt)
#pragma unroll
    for (int nt = 0; nt < 8; ++nt) acc[mt][nt] = zero4;

  for (int kb = 0; kb < 16; ++kb) {
    fp16x8 af[4];
#pragma unroll
    for (int mt = 0; mt < 4; ++mt) af[mt] = hfr[(kb * 4 + mt) * 64 + lane];
    fp16x8 bfr[8];
#pragma unroll
    for (int nt = 0; nt < 8; ++nt)
      bfr[nt] = w2p[((wave * 8 + nt) * 16 + kb) * 64 + lane];
#pragma unroll
    for (int mt = 0; mt < 4; ++mt)
#pragma unroll
      for (int nt = 0; nt < 8; ++nt)
        acc[mt][nt] = __builtin_amdgcn_mfma_f32_16x16x32_f16(af[mt], bfr[nt], acc[mt][nt], 0, 0, 0);
  }
#pragma unroll
  for (int nt = 0; nt < 8; ++nt) bv[nt] = b2[(wave * 8 + nt) * 16 + l15];

  __syncthreads();  // all waves done reading h1 frags

  // ---- epilogue2: relu + bias -> h2 frags (overwrite h1 region) ----
#pragma unroll
  for (int mt = 0; mt < 4; ++mt)
#pragma unroll
    for (int nt = 0; nt < 8; ++nt) {
      int kg = (wave * 8 + nt) * 16 + l15;
      int kb = kg >> 5, k32 = kg & 31;
      int lp = (k32 >> 3) << 4;
#pragma unroll
      for (int r = 0; r < 4; ++r) {
        float v = fmaxf(acc[mt][nt][r] + bv[nt], 0.f);
        hbuf[(((kb * 4 + mt) * 64) + ((quad * 4 + r) | lp)) * 8 + (k32 & 7)] = (_Float16)v;
      }
    }
  __syncthreads();

  // ---- layer3: out = h2 @ W3 (+b3, softplus). wave owns m-tile = wave, 5 n-tiles ----
  floatx4 acc3[5];
#pragma unroll
  for (int nt = 0; nt < 5; ++nt) acc3[nt] = zero4;
  for (int kb = 0; kb < 16; ++kb) {
    fp16x8 af = hfr[(kb * 4 + wave) * 64 + lane];
#pragma unroll
    for (int nt = 0; nt < 5; ++nt)
      acc3[nt] = __builtin_amdgcn_mfma_f32_16x16x32_f16(af, w3p[(nt * 16 + kb) * 64 + lane], acc3[nt], 0, 0, 0);
  }
  float b3v[5];
#pragma unroll
  for (int nt = 0; nt < 5; ++nt) {
    int col = nt * 16 + l15;
    b3v[nt] = (col < OUTC) ? b3[col] : 0.f;
  }
  __syncthreads();  // all waves done reading h2 frags

  // ---- epilogue3: softplus -> fp32 out tile [64][80] at LDS base ----
  float* outf = (float*)hbuf;
#pragma unroll
  for (int nt = 0; nt < 5; ++nt) {
    int col = nt * 16 + l15;
#pragma unroll
    for (int r = 0; r < 4; ++r) {
      if (col < OUTC) {
        float v = softplus_f(acc3[nt][r] + b3v[nt]);
        outf[(wave * 16 + quad * 4 + r) * 80 + col] = v;
      }
    }
  }
  __syncthreads();

  // ---- MMT = L L^T (masked 12-term dots) + c; fully coalesced stores ----
  const float* of = (const float*)hbuf;
  float* mmt = out + (size_t)r0 * 144;
#pragma unroll
  for (int s = 0; s < 36; ++s) {
    int e = tid + s * 256;          // 0..9215 over 64 rows x 144 entries
    int row = e / 144;
    int rem = e - row * 144;
    int i = rem / 12;
    int j = rem - i * 12;
    int kmax = (i < j) ? i : j;
    const float* Lr = of + row * 80;
    int ti = (i * (i + 1)) >> 1;
    int tj = (j * (j + 1)) >> 1;
    float ssum = 0.f;
#pragma unroll
    for (int k = 0; k < 12; ++k) {
      float a = (k <= kmax) ? Lr[ti + k] : 0.f;   // indices always < 80: in-bounds
      float b = Lr[tj + k];
      ssum = fmaf(a, b, ssum);
    }
    mmt[e] = ssum;
  }
  if (tid < 64) {
    out[(size_t)BATCH * 144 + r0 + tid] = of[tid * 80 + TRIC];
  }
}

extern "C" void kernel_launch(void* const* d_in, const int* in_sizes, int n_in,
                              void* d_out, int out_size, void* d_ws, size_t ws_size,
                              hipStream_t stream) {
  const float* x  = (const float*)d_in[0];
  const float* W1 = (const float*)d_in[1];
  const float* b1 = (const float*)d_in[2];
  const float* W2 = (const float*)d_in[3];
  const float* b2 = (const float*)d_in[4];
  const float* W3 = (const float*)d_in[5];
  const float* b3 = (const float*)d_in[6];
  float* out = (float*)d_out;
  _Float16* wsh = (_Float16*)d_ws;

  prep_kernel<<<156, 256, 0, stream>>>(W1, W2, W3, wsh);
  fused_kernel<<<BATCH / 64, 256, 0, stream>>>(x, b1, b2, b3, wsh, out);
}

// Round 2
// 500.871 us; speedup vs baseline: 1.1714x; 1.1714x over previous
//
#include <hip/hip_runtime.h>
#include <math.h>

typedef __attribute__((ext_vector_type(8))) _Float16 fp16x8;
typedef __attribute__((ext_vector_type(4))) float floatx4;

#define HID 512
#define TRIC 78
#define OUTC 79
#define BATCH 262144

// ws layout in halfs:
//   W1p frags: [0, 16384)          (32 ntile * 64 lane * 8)   K padded 12->32
//   W2p frags: [16384, 278528)     (32 ntile * 16 kb * 64 * 8)
//   W3p frags: [278528, 319488)    (5 ntile * 16 kb * 64 * 8) N padded 79->80
#define W2P_OFF 16384
#define W3P_OFF 278528

__global__ __launch_bounds__(256) void prep_kernel(const float* __restrict__ W1,
                                                   const float* __restrict__ W2,
                                                   const float* __restrict__ W3,
                                                   _Float16* __restrict__ wsh) {
  int g = blockIdx.x * 256 + threadIdx.x;
  int lane = g & 63;
  int l15 = lane & 15, q = lane >> 4;
  fp16x8 v;
  if (g < 2048) {
    // W1: 12x512, B-frag for 16x16x32: n = nt*16 + (lane&15), k = (lane>>4)*8 + j
    int nt = g >> 6;
    int n = nt * 16 + l15;
#pragma unroll
    for (int j = 0; j < 8; ++j) {
      int k = q * 8 + j;
      v[j] = (k < 12) ? (_Float16)W1[k * HID + n] : (_Float16)0.f;
    }
    *(fp16x8*)(wsh + (size_t)g * 8) = v;
  } else if (g < 34816) {
    // W2: 512x512
    int h = g - 2048;
    int fk = h >> 6;                 // fk = nt*16 + kb
    int kb = fk & 15, nt = fk >> 4;
    int n = nt * 16 + l15;
    int kbase = kb * 32 + q * 8;
#pragma unroll
    for (int j = 0; j < 8; ++j) v[j] = (_Float16)W2[(kbase + j) * HID + n];
    *(fp16x8*)(wsh + W2P_OFF + (size_t)h * 8) = v;
  } else if (g < 39936) {
    // W3: 512x79, pad N to 80
    int h = g - 34816;
    int fk = h >> 6;
    int kb = fk & 15, nt = fk >> 4;
    int n = nt * 16 + l15;
    int kbase = kb * 32 + q * 8;
#pragma unroll
    for (int j = 0; j < 8; ++j)
      v[j] = (n < OUTC) ? (_Float16)W3[(kbase + j) * OUTC + n] : (_Float16)0.f;
    *(fp16x8*)(wsh + W3P_OFF + (size_t)h * 8) = v;
  }
}

__device__ __forceinline__ float softplus_f(float v) {
  return fmaxf(v, 0.f) + log1pf(expf(-fabsf(v)));
}

// hbuf A-frag layout: half index = ((kb*4 + mt)*64 + lane')*8 + j'
// encodes h[m = mt*16 + (lane'&15)][k = kb*32 + (lane'>>4)*8 + j']
__global__ __launch_bounds__(256, 2) void fused_kernel(const float* __restrict__ x,
                                                       const float* __restrict__ b1,
                                                       const float* __restrict__ b2,
                                                       const float* __restrict__ b3,
                                                       const _Float16* __restrict__ wsh,
                                                       float* __restrict__ out) {
  __shared__ _Float16 hbuf[32768];  // 64 KB: h-frags, overlaid with x stage / out tile
  const int tid = threadIdx.x;
  const int wave = tid >> 6, lane = tid & 63;
  const int l15 = lane & 15, quad = lane >> 4;
  const int r0 = blockIdx.x * 64;

  // ---- stage x tile (64 rows x 12 f32, coalesced) into LDS base ----
  float* xf = (float*)hbuf;
  const float* xg = x + (size_t)r0 * 12;
#pragma unroll
  for (int s = 0; s < 3; ++s) xf[tid + s * 256] = xg[tid + s * 256];
  __syncthreads();

  // ---- layer1 A-frags from x (K padded to 32) ----
  fp16x8 xa[4];
#pragma unroll
  for (int mt = 0; mt < 4; ++mt) {
    int row = mt * 16 + l15;
#pragma unroll
    for (int j = 0; j < 8; ++j) {
      int k = quad * 8 + j;
      xa[mt][j] = (k < 12) ? (_Float16)xf[row * 12 + k] : (_Float16)0.f;
    }
  }

  const fp16x8* w1p = (const fp16x8*)wsh;
  const fp16x8* w2p = (const fp16x8*)(wsh + W2P_OFF);
  const fp16x8* w3p = (const fp16x8*)(wsh + W3P_OFF);
  const fp16x8* hfr = (const fp16x8*)hbuf;

  const floatx4 zero4 = {0.f, 0.f, 0.f, 0.f};
  floatx4 acc[4][8];
#pragma unroll
  for (int mt = 0; mt < 4; ++mt)
#pragma unroll
    for (int nt = 0; nt < 8; ++nt) acc[mt][nt] = zero4;

  // ---- layer1 MFMA: h1 = relu(x @ W1 + b1); wave owns 128-col slice ----
#pragma unroll
  for (int nt = 0; nt < 8; ++nt) {
    int ntw = wave * 8 + nt;
    fp16x8 bf = w1p[ntw * 64 + lane];
#pragma unroll
    for (int mt = 0; mt < 4; ++mt)
      acc[mt][nt] = __builtin_amdgcn_mfma_f32_16x16x32_f16(xa[mt], bf, acc[mt][nt], 0, 0, 0);
  }
  float bv[8];
#pragma unroll
  for (int nt = 0; nt < 8; ++nt) bv[nt] = b1[(wave * 8 + nt) * 16 + l15];

  __syncthreads();  // all waves done reading x region

  // ---- epilogue1: relu + bias -> h-frag layout in LDS (fp16) ----
#pragma unroll
  for (int mt = 0; mt < 4; ++mt)
#pragma unroll
    for (int nt = 0; nt < 8; ++nt) {
      int kg = (wave * 8 + nt) * 16 + l15;
      int kb = kg >> 5, k32 = kg & 31;
      int lp = (k32 >> 3) << 4;
#pragma unroll
      for (int r = 0; r < 4; ++r) {
        float v = fmaxf(acc[mt][nt][r] + bv[nt], 0.f);
        hbuf[(((kb * 4 + mt) * 64) + ((quad * 4 + r) | lp)) * 8 + (k32 & 7)] = (_Float16)v;
      }
    }
  __syncthreads();

  // ---- layer2: h2 = relu(h1 @ W2 + b2). No barrier in K-loop; W2 frags from L2 ----
#pragma unroll
  for (int mt = 0; mt < 4; ++mt)
#pragma unroll
    for (int nt = 0; nt < 8; ++nt) acc[mt][nt] = zero4;

  for (int kb = 0; kb < 16; ++kb) {
    fp16x8 af[4];
#pragma unroll
    for (int mt = 0; mt < 4; ++mt) af[mt] = hfr[(kb * 4 + mt) * 64 + lane];
    fp16x8 bfr[8];
#pragma unroll
    for (int nt = 0; nt < 8; ++nt)
      bfr[nt] = w2p[((wave * 8 + nt) * 16 + kb) * 64 + lane];
#pragma unroll
    for (int mt = 0; mt < 4; ++mt)
#pragma unroll
      for (int nt = 0; nt < 8; ++nt)
        acc[mt][nt] = __builtin_amdgcn_mfma_f32_16x16x32_f16(af[mt], bfr[nt], acc[mt][nt], 0, 0, 0);
  }
#pragma unroll
  for (int nt = 0; nt < 8; ++nt) bv[nt] = b2[(wave * 8 + nt) * 16 + l15];

  __syncthreads();  // all waves done reading h1 frags

  // ---- epilogue2: relu + bias -> h2 frags (overwrite h1 region) ----
#pragma unroll
  for (int mt = 0; mt < 4; ++mt)
#pragma unroll
    for (int nt = 0; nt < 8; ++nt) {
      int kg = (wave * 8 + nt) * 16 + l15;
      int kb = kg >> 5, k32 = kg & 31;
      int lp = (k32 >> 3) << 4;
#pragma unroll
      for (int r = 0; r < 4; ++r) {
        float v = fmaxf(acc[mt][nt][r] + bv[nt], 0.f);
        hbuf[(((kb * 4 + mt) * 64) + ((quad * 4 + r) | lp)) * 8 + (k32 & 7)] = (_Float16)v;
      }
    }
  __syncthreads();

  // ---- layer3: out = h2 @ W3 (+b3, softplus). wave owns m-tile = wave, 5 n-tiles ----
  floatx4 acc3[5];
#pragma unroll
  for (int nt = 0; nt < 5; ++nt) acc3[nt] = zero4;
  for (int kb = 0; kb < 16; ++kb) {
    fp16x8 af = hfr[(kb * 4 + wave) * 64 + lane];
#pragma unroll
    for (int nt = 0; nt < 5; ++nt)
      acc3[nt] = __builtin_amdgcn_mfma_f32_16x16x32_f16(af, w3p[(nt * 16 + kb) * 64 + lane], acc3[nt], 0, 0, 0);
  }
  float b3v[5];
#pragma unroll
  for (int nt = 0; nt < 5; ++nt) {
    int col = nt * 16 + l15;
    b3v[nt] = (col < OUTC) ? b3[col] : 0.f;
  }
  __syncthreads();  // all waves done reading h2 frags

  // ---- epilogue3: softplus -> fp32 out tile [64][81] (stride 81: 17*row mod 32
  // hits 16 distinct banks for 16 rows -> conflict-free MMT reads) ----
  float* outf = (float*)hbuf;
#pragma unroll
  for (int nt = 0; nt < 5; ++nt) {
    int col = nt * 16 + l15;
#pragma unroll
    for (int r = 0; r < 4; ++r) {
      if (col < OUTC) {
        float v = softplus_f(acc3[nt][r] + b3v[nt]);
        outf[(wave * 16 + quad * 4 + r) * 81 + col] = v;
      }
    }
  }
  __syncthreads();

  // ---- MMT = L L^T, register-resident. 4 threads/row; thread owns cols
  // j in {sub, sub+4, sub+8}. Zero-padded Lj columns make
  // sum_{k<=i} Li[k]*Lj[k] == sum_{k<=min(i,j)} automatically. ----
  const float* of = (const float*)hbuf;
  const int rowl = tid >> 2;   // 0..63
  const int sub = tid & 3;
  const float* Lr = of + rowl * 81;

  float Lj[3][12];
#pragma unroll
  for (int t = 0; t < 3; ++t) {
    int j = sub + 4 * t;
    int tj = (j * (j + 1)) >> 1;
#pragma unroll
    for (int k = 0; k < 12; ++k) {
      float v = Lr[tj + k];              // always in-bounds (< 78)
      Lj[t][k] = (k <= j) ? v : 0.f;
    }
  }

  float* mmt = out + (size_t)(r0 + rowl) * 144;
#pragma unroll
  for (int i = 0; i < 12; ++i) {
    int ti = (i * (i + 1)) >> 1;
    float Li[12];
#pragma unroll
    for (int k = 0; k <= i; ++k) Li[k] = Lr[ti + k];
#pragma unroll
    for (int t = 0; t < 3; ++t) {
      float s = 0.f;
#pragma unroll
      for (int k = 0; k <= i; ++k) s = fmaf(Li[k], Lj[t][k], s);
      __builtin_nontemporal_store(s, mmt + i * 12 + sub + 4 * t);
    }
  }
  if (sub == 0) {
    __builtin_nontemporal_store(Lr[TRIC], out + (size_t)BATCH * 144 + r0 + rowl);
  }
}

extern "C" void kernel_launch(void* const* d_in, const int* in_sizes, int n_in,
                              void* d_out, int out_size, void* d_ws, size_t ws_size,
                              hipStream_t stream) {
  const float* x  = (const float*)d_in[0];
  const float* W1 = (const float*)d_in[1];
  const float* b1 = (const float*)d_in[2];
  const float* W2 = (const float*)d_in[3];
  const float* b2 = (const float*)d_in[4];
  const float* W3 = (const float*)d_in[5];
  const float* b3 = (const float*)d_in[6];
  float* out = (float*)d_out;
  _Float16* wsh = (_Float16*)d_ws;

  prep_kernel<<<156, 256, 0, stream>>>(W1, W2, W3, wsh);
  fused_kernel<<<BATCH / 64, 256, 0, stream>>>(x, b1, b2, b3, wsh, out);
}